// Round 3
// baseline (1643.598 us; speedup 1.0000x reference)
//
#include <hip/hip_runtime.h>

#define NV 8192
#define NC 128
#define VP 64
#define FP 124
#define NBLK 128
#define NTHR 256
#define MAXSLOT 26   // hard bound: bbox half-extent <= 0.5, spacing 0.8 -> <=26 neighbors

typedef unsigned long long ull;

// Device-scope sense barrier. bar[0]=count, bar[1]=generation. Zeroed by
// hipMemsetAsync before launch. 128 blocks on 256 CUs are always co-resident.
__device__ __forceinline__ void gridbar(int* bar) {
  __syncthreads();
  if (threadIdx.x == 0) {
    __threadfence();  // release: make this block's global writes visible
    int g = __hip_atomic_load(bar + 1, __ATOMIC_RELAXED, __HIP_MEMORY_SCOPE_AGENT);
    int old = __hip_atomic_fetch_add(bar, 1, __ATOMIC_ACQ_REL, __HIP_MEMORY_SCOPE_AGENT);
    if (old == NBLK - 1) {
      __hip_atomic_store(bar, 0, __ATOMIC_RELAXED, __HIP_MEMORY_SCOPE_AGENT);
      __hip_atomic_fetch_add(bar + 1, 1, __ATOMIC_RELEASE, __HIP_MEMORY_SCOPE_AGENT);
    } else {
      while (__hip_atomic_load(bar + 1, __ATOMIC_RELAXED, __HIP_MEMORY_SCOPE_AGENT) == g)
        __builtin_amdgcn_s_sleep(2);
    }
    __threadfence();  // acquire: invalidate stale L1/L2 before re-reading others' data
  }
  __syncthreads();
}

__global__ __launch_bounds__(NTHR, 1)
void soap_fused(const float* __restrict__ bb, const float* __restrict__ pP,
                const float* __restrict__ pS, const int* __restrict__ faces,
                const int* __restrict__ cfl,
                float* __restrict__ verts, int* __restrict__ labels2,
                float* __restrict__ sums1, float* __restrict__ counts1,
                float* __restrict__ sums2, ull* __restrict__ masks,
                int* bar) {
  const float T2 = (float)(0.3 * 0.3);
  const int c = blockIdx.x;
  const int t = threadIdx.x;
  const int q = t >> 6;   // wave id 0..3
  const int v = t & 63;   // lane id

  __shared__ float s_vx[VP], s_vy[VP], s_vz[VP], s_sq[VP];
  __shared__ float s_gx[VP], s_gy[VP], s_gz[VP];
  __shared__ float s_fx[VP], s_fy[VP], s_fz[VP];
  __shared__ int   s_nm[VP], s_lab[VP];
  __shared__ int   s_jl[(MAXSLOT + 1) * VP];
  __shared__ int   s_cellmin[MAXSLOT];
  __shared__ int   s_adjcell[MAXSLOT];
  __shared__ int   s_Ksh;
  __shared__ ull   s_adjw[2];
  __shared__ float s_cx, s_cy, s_cz, s_vol, s_csx, s_csy, s_csz;

  // ---- adjacency from bboxes (constant across iterations) ----
  if (q < 2) {
    int b = q * 64 + v;
    float anx = bb[c*6+0], any_ = bb[c*6+1], anz = bb[c*6+2];
    float axx = bb[c*6+3], axy = bb[c*6+4], axz = bb[c*6+5];
    float bnx = bb[b*6+0], bny = bb[b*6+1], bnz = bb[b*6+2];
    float bxx = bb[b*6+3], bxy = bb[b*6+4], bxz = bb[b*6+5];
    bool ov = (b != c) && (anx <= bxx) && (any_ <= bxy) && (anz <= bxz) &&
              (bnx <= axx) && (bny <= axy) && (bnz <= axz);
    ull w = __ballot(ov);
    if (v == 0) s_adjw[q] = w;
  }
  __syncthreads();
  if (t == 0) {
    int slot = 0;
    for (int wd = 0; wd < 2; ++wd) {
      ull aw = s_adjw[wd];
      while (aw) {
        int bbit = __ffsll((long long)aw) - 1; aw &= aw - 1;
        if (slot < MAXSLOT) s_adjcell[slot] = wd * 64 + bbit;
        ++slot;
      }
    }
    s_Ksh = slot;   // provably <= 26
  }
  __syncthreads();
  const int K = s_Ksh;

  for (int it = 0; it < 5; ++it) {
    // ================= PHASE 1: stage + zero + mask build + UF round 1 =========
    if (t < VP) {
      int i = c*VP + t;
      float x = verts[3*i], y = verts[3*i+1], z = verts[3*i+2];
      s_vx[t] = x; s_vy[t] = y; s_vz[t] = z; s_sq[t] = x*x + y*y + z*z;
      s_nm[t] = i;            // identity label
      counts1[i] = 0.f;
    }
    for (int idx = t; idx < VP*3; idx += NTHR) {
      sums1[c*VP*3 + idx] = 0.f;
      sums2[c*VP*3 + idx] = 0.f;
    }
    __syncthreads();
    {
      int pmv = NV;
      for (int slot = q; slot < K; slot += 4) {
        int bcell = s_adjcell[slot];
        int j = bcell*VP + v;
        float xj = verts[3*j], yj = verts[3*j+1], zj = verts[3*j+2];
        float sqj = xj*xj + yj*yj + zj*zj;
        ull* mrow = masks + ((size_t)c*MAXSLOT + slot)*VP;
        for (int vv = 0; vv < VP; ++vv) {
          float d2 = s_sq[vv] + sqj - 2.f*(s_vx[vv]*xj + s_vy[vv]*yj + s_vz[vv]*zj);
          ull w = __ballot(d2 < T2);
          if (v == vv) {
            mrow[vv] = w;
            if (w) pmv = min(pmv, bcell*VP + __ffsll((long long)w) - 1);
          }
        }
      }
      atomicMin(&s_nm[v], pmv);
    }
    __syncthreads();
    if (t < VP) labels2[c*VP + t] = s_nm[t];
    gridbar(bar);

    // ================= PHASES 2..8: UF rounds (1 sync each) ====================
    for (int r = 1; r < 8; ++r) {
      // stage jumped labels jl[j]=labels2[labels2[j]] for own + adjacent cells
      for (int slot = q; slot <= K; slot += 4) {
        int bcell = (slot == K) ? c : s_adjcell[slot];
        int x = labels2[bcell*VP + v];
        int jl = labels2[x];
        s_jl[slot*VP + v] = jl;
        int mm = jl;
#pragma unroll
        for (int o = 32; o; o >>= 1) mm = min(mm, __shfl_xor(mm, o));
        if (v == 0 && slot < K) s_cellmin[slot] = mm;
      }
      __syncthreads();
      if (t < VP) s_nm[t] = s_jl[K*VP + t];   // init with own jumped label
      __syncthreads();
      {
        int pm = NV;
        for (int slot = q; slot < K; slot += 4) {
          ull w = masks[((size_t)c*MAXSLOT + slot)*VP + v];
          if (w == ~0ull) pm = min(pm, s_cellmin[slot]);
          else {
            while (w) {
              int bt = __ffsll((long long)w) - 1; w &= w - 1;
              pm = min(pm, s_jl[slot*VP + bt]);
            }
          }
        }
        atomicMin(&s_nm[v], pm);
      }
      __syncthreads();
      if (t < VP) labels2[c*VP + t] = s_nm[t];
      gridbar(bar);
    }

    // ================= PHASE 9: final jump + scatter(verts) ====================
    if (t < VP) {
      int x = labels2[c*VP + t];
      s_lab[t] = labels2[x];
    }
    __syncthreads();
    if (t < VP) {
      int l = s_lab[t];
      bool leader = true;
      for (int s = 0; s < t; ++s) if (s_lab[s] == l) { leader = false; break; }
      if (leader) {
        float sx = 0.f, sy = 0.f, sz = 0.f, cn = 0.f;
        for (int s = t; s < VP; ++s)
          if (s_lab[s] == l) { sx += s_vx[s]; sy += s_vy[s]; sz += s_vz[s]; cn += 1.f; }
        atomicAdd(&sums1[3*l+0], sx);
        atomicAdd(&sums1[3*l+1], sy);
        atomicAdd(&sums1[3*l+2], sz);
        atomicAdd(&counts1[l], cn);
      }
    }
    gridbar(bar);

    // ======== PHASE 10: gather_replace + cell forces + scatter(forces) =========
    if (t < VP) {
      int l = s_lab[t];
      float cc = fmaxf(counts1[l], 1.f);
      s_vx[t] = sums1[3*l+0] / cc;
      s_vy[t] = sums1[3*l+1] / cc;
      s_vz[t] = sums1[3*l+2] / cc;
      s_gx[t] = 0.f; s_gy[t] = 0.f; s_gz[t] = 0.f;
    }
    if (t == 0) { s_vol = 0.f; s_csx = 0.f; s_csy = 0.f; s_csz = 0.f; }
    __syncthreads();
    if (t < VP) {
      float sx = s_vx[t], sy = s_vy[t], sz = s_vz[t];
#pragma unroll
      for (int o = 32; o; o >>= 1) { sx += __shfl_xor(sx, o); sy += __shfl_xor(sy, o); sz += __shfl_xor(sz, o); }
      if (t == 0) { s_cx = sx*(1.f/VP); s_cy = sy*(1.f/VP); s_cz = sz*(1.f/VP); }
    }
    __syncthreads();
    {
      float cx = s_cx, cy = s_cy, cz = s_cz;
      bool act = (t < FP);
      int ia = 0, ib = 0, ic = 0;
      float p0x=0,p0y=0,p0z=0,p1x=0,p1y=0,p1z=0,p2x=0,p2y=0,p2z=0;
      float q0x=0,q0y=0,q0z=0;
      if (act) {
        int f = cfl[c*FP + t];
        ia = faces[3*f+0] - c*VP; ib = faces[3*f+1] - c*VP; ic = faces[3*f+2] - c*VP;
        p0x = s_vx[ia]-cx; p0y = s_vy[ia]-cy; p0z = s_vz[ia]-cz;
        p1x = s_vx[ib]-cx; p1y = s_vy[ib]-cy; p1z = s_vz[ib]-cz;
        p2x = s_vx[ic]-cx; p2y = s_vy[ic]-cy; p2z = s_vz[ic]-cz;
        q0x = p1y*p2z - p1z*p2y;
        q0y = p1z*p2x - p1x*p2z;
        q0z = p1x*p2y - p1y*p2x;
        float term = p0x*q0x + p0y*q0y + p0z*q0z;
        atomicAdd(&s_vol, term);
      }
      __syncthreads();
      float press = pP[0]*190.f + 10.f;
      float st    = pS[0]*0.018f + 0.002f;
      float tv    = expf(press / 2500.f);
      float vol   = s_vol / 6.f;
      float coeff = 2500.f * (vol - tv);
      if (act) {
        float q1x = p2y*p0z - p2z*p0y;
        float q1y = p2z*p0x - p2x*p0z;
        float q1z = p2x*p0y - p2y*p0x;
        float q2x = p0y*p1z - p0z*p1y;
        float q2y = p0z*p1x - p0x*p1z;
        float q2z = p0x*p1y - p0y*p1x;
        float e1x = p1x-p0x, e1y = p1y-p0y, e1z = p1z-p0z;
        float e2x = p2x-p0x, e2y = p2y-p0y, e2z = p2z-p0z;
        float nx = e1y*e2z - e1z*e2y;
        float ny = e1z*e2x - e1x*e2z;
        float nz = e1x*e2y - e1y*e2x;
        float S  = nx*nx + ny*ny + nz*nz + 1e-12f;
        float wt = st / (2.f * sqrtf(S));
        float dx = e1x-e2x, dy = e1y-e2y, dz = e1z-e2z;
        float g0x = wt*(dy*nz - dz*ny), g0y = wt*(dz*nx - dx*nz), g0z = wt*(dx*ny - dy*nx);
        float g1x = wt*(e2y*nz - e2z*ny), g1y = wt*(e2z*nx - e2x*nz), g1z = wt*(e2x*ny - e2y*nx);
        float g2x = wt*(ny*e1z - nz*e1y), g2y = wt*(nz*e1x - nx*e1z), g2z = wt*(nx*e1y - ny*e1x);
        float k = coeff / 6.f;
        atomicAdd(&s_gx[ia], g0x + k*q0x); atomicAdd(&s_gy[ia], g0y + k*q0y); atomicAdd(&s_gz[ia], g0z + k*q0z);
        atomicAdd(&s_gx[ib], g1x + k*q1x); atomicAdd(&s_gy[ib], g1y + k*q1y); atomicAdd(&s_gz[ib], g1z + k*q1z);
        atomicAdd(&s_gx[ic], g2x + k*q2x); atomicAdd(&s_gy[ic], g2y + k*q2y); atomicAdd(&s_gz[ic], g2z + k*q2z);
        atomicAdd(&s_csx, q0x+q1x+q2x);
        atomicAdd(&s_csy, q0y+q1y+q2y);
        atomicAdd(&s_csz, q0z+q1z+q2z);
      }
      __syncthreads();
      if (t < VP) {
        float corr = coeff / 384.f;   // coeff * (1/6) * (1/64) centroid chain
        s_fx[t] = -(s_gx[t] - corr*s_csx);
        s_fy[t] = -(s_gy[t] - corr*s_csy);
        s_fz[t] = -(s_gz[t] - corr*s_csz);
      }
    }
    __syncthreads();
    if (t < VP) {
      int l = s_lab[t];
      bool leader = true;
      for (int s = 0; s < t; ++s) if (s_lab[s] == l) { leader = false; break; }
      if (leader) {
        float sx = 0.f, sy = 0.f, sz = 0.f;
        for (int s = t; s < VP; ++s)
          if (s_lab[s] == l) { sx += s_fx[s]; sy += s_fy[s]; sz += s_fz[s]; }
        atomicAdd(&sums2[3*l+0], sx);
        atomicAdd(&sums2[3*l+1], sy);
        atomicAdd(&sums2[3*l+2], sz);
      }
    }
    gridbar(bar);

    // ================= PHASE 11: Euler update ==================================
    if (t < VP) {
      int i = c*VP + t;
      int l = s_lab[t];
      float cc = fmaxf(counts1[l], 1.f);
      verts[3*i+0] = s_vx[t] + 1e-5f*(sums2[3*l+0]/cc);
      verts[3*i+1] = s_vy[t] + 1e-5f*(sums2[3*l+1]/cc);
      verts[3*i+2] = s_vz[t] + 1e-5f*(sums2[3*l+2]/cc);
    }
    gridbar(bar);
  }
}

extern "C" void kernel_launch(void* const* d_in, const int* in_sizes, int n_in,
                              void* d_out, int out_size, void* d_ws, size_t ws_size,
                              hipStream_t stream) {
  const float* inV   = (const float*)d_in[0];
  const float* bb    = (const float*)d_in[1];
  const float* pP    = (const float*)d_in[2];
  const float* pS    = (const float*)d_in[3];
  const int*   faces = (const int*)d_in[4];
  const int*   cfl   = (const int*)d_in[6];

  char* w = (char*)d_ws;
  float* verts   = (float*)w; w += NV*3*sizeof(float);    // 96 KB
  int*   labels2 = (int*)w;   w += NV*sizeof(int);        // 32 KB
  float* sums1   = (float*)w; w += NV*3*sizeof(float);    // 96 KB
  float* counts1 = (float*)w; w += NV*sizeof(float);      // 32 KB
  float* sums2   = (float*)w; w += NV*3*sizeof(float);    // 96 KB
  ull*   masks   = (ull*)w;   w += (size_t)NC*MAXSLOT*VP*sizeof(ull);  // 1.66 MB
  int*   bar     = (int*)w;   w += 2*sizeof(int);

  hipMemsetAsync(bar, 0, 2*sizeof(int), stream);
  hipMemcpyAsync(verts, inV, NV*3*sizeof(float), hipMemcpyDeviceToDevice, stream);
  soap_fused<<<NBLK, NTHR, 0, stream>>>(bb, pP, pS, faces, cfl,
                                        verts, labels2, sums1, counts1,
                                        sums2, masks, bar);
  hipMemcpyAsync(d_out, verts, NV*3*sizeof(float), hipMemcpyDeviceToDevice, stream);
}

// Round 4
// 1137.639 us; speedup vs baseline: 1.4447x; 1.4447x over previous
//
#include <hip/hip_runtime.h>

#define NV 8192
#define NC 128
#define VP 64
#define FP 124
#define NBLK 128
#define NTHR 256
#define MAXSLOT 26   // bbox half-extent <= 0.5, spacing 0.8 -> <=26 neighbors

typedef unsigned long long ull;

// Coherent (MALL-level) accessors: compile to global_load/store with sc1,
// bypassing the non-coherent per-XCD L2. No fences needed anywhere.
__device__ __forceinline__ float ald(const float* p) {
  return __hip_atomic_load(p, __ATOMIC_RELAXED, __HIP_MEMORY_SCOPE_AGENT);
}
__device__ __forceinline__ int aldi(const int* p) {
  return __hip_atomic_load(p, __ATOMIC_RELAXED, __HIP_MEMORY_SCOPE_AGENT);
}
__device__ __forceinline__ void ast(float* p, float v) {
  __hip_atomic_store(p, v, __ATOMIC_RELAXED, __HIP_MEMORY_SCOPE_AGENT);
}
__device__ __forceinline__ void asti(int* p, int v) {
  __hip_atomic_store(p, v, __ATOMIC_RELAXED, __HIP_MEMORY_SCOPE_AGENT);
}

// Fence-free grid barrier: per-block slot + monotone sequence. All shared
// data is sc1 (coherent at MALL), so visibility = vmcnt(0) drain + slot store.
__device__ __forceinline__ void gridbar(int* slots, int seq, int c, int t) {
  asm volatile("s_waitcnt vmcnt(0)" ::: "memory");
  __syncthreads();
  if (t == 0) asti(&slots[c], seq);
  if (t < NBLK) {
    while (aldi(&slots[t]) < seq) __builtin_amdgcn_s_sleep(1);
  }
  asm volatile("" ::: "memory");
  __syncthreads();
}

__global__ __launch_bounds__(NTHR, 1)
void soap_fused(const float* __restrict__ bb, const float* __restrict__ pP,
                const float* __restrict__ pS, const int* __restrict__ faces,
                const int* __restrict__ cfl,
                float* __restrict__ verts, int* __restrict__ labels2,
                float* __restrict__ sums1, float* __restrict__ counts1,
                float* __restrict__ sums2, ull* __restrict__ masks,
                int* slots) {
  const float T2 = (float)(0.3 * 0.3);
  const int c = blockIdx.x;
  const int t = threadIdx.x;
  const int q = t >> 6;   // wave id 0..3
  const int v = t & 63;   // lane id

  __shared__ float s_vx[VP], s_vy[VP], s_vz[VP], s_sq[VP];
  __shared__ float s_gx[VP], s_gy[VP], s_gz[VP];
  __shared__ float s_fx[VP], s_fy[VP], s_fz[VP];
  __shared__ int   s_nm[VP], s_lab[VP];
  __shared__ int   s_jl[(MAXSLOT + 1) * VP];
  __shared__ int   s_cellmin[MAXSLOT];
  __shared__ int   s_adjcell[MAXSLOT];
  __shared__ int   s_Ksh;
  __shared__ ull   s_adjw[2];
  __shared__ float s_cx, s_cy, s_cz, s_vol, s_csx, s_csy, s_csz;

  int seq = 0;

  // ---- adjacency from bboxes (constant across iterations) ----
  if (q < 2) {
    int b = q * 64 + v;
    float anx = bb[c*6+0], any_ = bb[c*6+1], anz = bb[c*6+2];
    float axx = bb[c*6+3], axy = bb[c*6+4], axz = bb[c*6+5];
    float bnx = bb[b*6+0], bny = bb[b*6+1], bnz = bb[b*6+2];
    float bxx = bb[b*6+3], bxy = bb[b*6+4], bxz = bb[b*6+5];
    bool ov = (b != c) && (anx <= bxx) && (any_ <= bxy) && (anz <= bxz) &&
              (bnx <= axx) && (bny <= axy) && (bnz <= axz);
    ull w = __ballot(ov);
    if (v == 0) s_adjw[q] = w;
  }
  __syncthreads();
  if (t == 0) {
    int slot = 0;
    for (int wd = 0; wd < 2; ++wd) {
      ull aw = s_adjw[wd];
      while (aw) {
        int bbit = __ffsll((long long)aw) - 1; aw &= aw - 1;
        if (slot < MAXSLOT) s_adjcell[slot] = wd * 64 + bbit;
        ++slot;
      }
    }
    s_Ksh = slot;   // provably <= 26
  }
  __syncthreads();
  const int K = s_Ksh;

  for (int it = 0; it < 5; ++it) {
    // ===== PHASE 1: stage + zero sums + mask build + UF round 1 ======
    if (t < VP) {
      int i = c*VP + t;
      float x = ald(&verts[3*i]), y = ald(&verts[3*i+1]), z = ald(&verts[3*i+2]);
      s_vx[t] = x; s_vy[t] = y; s_vz[t] = z; s_sq[t] = x*x + y*y + z*z;
      s_nm[t] = i;            // identity label
      ast(&counts1[i], 0.f);
    }
    for (int idx = t; idx < VP*3; idx += NTHR) {
      ast(&sums1[c*VP*3 + idx], 0.f);
      ast(&sums2[c*VP*3 + idx], 0.f);
    }
    __syncthreads();
    {
      int pmv = NV;
      for (int slot = q; slot < K; slot += 4) {
        int bcell = s_adjcell[slot];
        int j = bcell*VP + v;
        float xj = ald(&verts[3*j]), yj = ald(&verts[3*j+1]), zj = ald(&verts[3*j+2]);
        float sqj = xj*xj + yj*yj + zj*zj;
        ull myw = 0;
        for (int vv = 0; vv < VP; ++vv) {
          float d2 = s_sq[vv] + sqj - 2.f*(s_vx[vv]*xj + s_vy[vv]*yj + s_vz[vv]*zj);
          ull w = __ballot(d2 < T2);
          if (v == vv) myw = w;
        }
        masks[((size_t)c*MAXSLOT + slot)*VP + v] = myw;  // block-private, plain
        if (myw) pmv = min(pmv, bcell*VP + __ffsll((long long)myw) - 1);
      }
      atomicMin(&s_nm[v], pmv);
    }
    __syncthreads();
    if (t < VP) asti(&labels2[c*VP + t], s_nm[t]);
    gridbar(slots, ++seq, c, t);

    // ===== PHASES 2..8: UF rounds (1 barrier each) =====================
    for (int r = 1; r < 8; ++r) {
      // stage jumped labels jl[j]=labels2[labels2[j]] for own + adjacent cells
      for (int slot = q; slot <= K; slot += 4) {
        int bcell = (slot == K) ? c : s_adjcell[slot];
        int x = aldi(&labels2[bcell*VP + v]);
        int jl = aldi(&labels2[x]);
        s_jl[slot*VP + v] = jl;
        int mm = jl;
#pragma unroll
        for (int o = 32; o; o >>= 1) mm = min(mm, __shfl_xor(mm, o));
        if (v == 0 && slot < K) s_cellmin[slot] = mm;
      }
      __syncthreads();
      if (t < VP) s_nm[t] = s_jl[K*VP + t];   // own jumped label
      __syncthreads();
      {
        int pm = NV;
        for (int slot = q; slot < K; slot += 4) {
          ull w = masks[((size_t)c*MAXSLOT + slot)*VP + v];
          if (w == ~0ull) pm = min(pm, s_cellmin[slot]);
          else {
            while (w) {
              int bt = __ffsll((long long)w) - 1; w &= w - 1;
              pm = min(pm, s_jl[slot*VP + bt]);
            }
          }
        }
        atomicMin(&s_nm[v], pm);
      }
      __syncthreads();
      if (t < VP) asti(&labels2[c*VP + t], s_nm[t]);
      gridbar(slots, ++seq, c, t);
    }

    // ===== PHASE 9: final jump + scatter(verts) ========================
    if (t < VP) s_lab[t] = aldi(&labels2[s_nm[t]]);   // labels2[own]==s_nm
    __syncthreads();
    if (t < VP) {
      int l = s_lab[t];
      bool leader = true;
      for (int s = 0; s < t; ++s) if (s_lab[s] == l) { leader = false; break; }
      if (leader) {
        float sx = 0.f, sy = 0.f, sz = 0.f, cn = 0.f;
        for (int s = t; s < VP; ++s)
          if (s_lab[s] == l) { sx += s_vx[s]; sy += s_vy[s]; sz += s_vz[s]; cn += 1.f; }
        atomicAdd(&sums1[3*l+0], sx);
        atomicAdd(&sums1[3*l+1], sy);
        atomicAdd(&sums1[3*l+2], sz);
        atomicAdd(&counts1[l], cn);
      }
    }
    gridbar(slots, ++seq, c, t);

    // ===== PHASE 10: gather_replace + cell forces + scatter(forces) ====
    if (t < VP) {
      int l = s_lab[t];
      float cc = fmaxf(ald(&counts1[l]), 1.f);
      s_vx[t] = ald(&sums1[3*l+0]) / cc;
      s_vy[t] = ald(&sums1[3*l+1]) / cc;
      s_vz[t] = ald(&sums1[3*l+2]) / cc;
      s_gx[t] = 0.f; s_gy[t] = 0.f; s_gz[t] = 0.f;
    }
    if (t == 0) { s_vol = 0.f; s_csx = 0.f; s_csy = 0.f; s_csz = 0.f; }
    __syncthreads();
    if (t < VP) {
      float sx = s_vx[t], sy = s_vy[t], sz = s_vz[t];
#pragma unroll
      for (int o = 32; o; o >>= 1) { sx += __shfl_xor(sx, o); sy += __shfl_xor(sy, o); sz += __shfl_xor(sz, o); }
      if (t == 0) { s_cx = sx*(1.f/VP); s_cy = sy*(1.f/VP); s_cz = sz*(1.f/VP); }
    }
    __syncthreads();
    {
      float cx = s_cx, cy = s_cy, cz = s_cz;
      bool act = (t < FP);
      int ia = 0, ib = 0, ic = 0;
      float p0x=0,p0y=0,p0z=0,p1x=0,p1y=0,p1z=0,p2x=0,p2y=0,p2z=0;
      float q0x=0,q0y=0,q0z=0;
      if (act) {
        int f = cfl[c*FP + t];
        ia = faces[3*f+0] - c*VP; ib = faces[3*f+1] - c*VP; ic = faces[3*f+2] - c*VP;
        p0x = s_vx[ia]-cx; p0y = s_vy[ia]-cy; p0z = s_vz[ia]-cz;
        p1x = s_vx[ib]-cx; p1y = s_vy[ib]-cy; p1z = s_vz[ib]-cz;
        p2x = s_vx[ic]-cx; p2y = s_vy[ic]-cy; p2z = s_vz[ic]-cz;
        q0x = p1y*p2z - p1z*p2y;
        q0y = p1z*p2x - p1x*p2z;
        q0z = p1x*p2y - p1y*p2x;
        float term = p0x*q0x + p0y*q0y + p0z*q0z;
        atomicAdd(&s_vol, term);
      }
      __syncthreads();
      float press = pP[0]*190.f + 10.f;
      float st    = pS[0]*0.018f + 0.002f;
      float tv    = expf(press / 2500.f);
      float vol   = s_vol / 6.f;
      float coeff = 2500.f * (vol - tv);
      if (act) {
        float q1x = p2y*p0z - p2z*p0y;
        float q1y = p2z*p0x - p2x*p0z;
        float q1z = p2x*p0y - p2y*p0x;
        float q2x = p0y*p1z - p0z*p1y;
        float q2y = p0z*p1x - p0x*p1z;
        float q2z = p0x*p1y - p0y*p1x;
        float e1x = p1x-p0x, e1y = p1y-p0y, e1z = p1z-p0z;
        float e2x = p2x-p0x, e2y = p2y-p0y, e2z = p2z-p0z;
        float nx = e1y*e2z - e1z*e2y;
        float ny = e1z*e2x - e1x*e2z;
        float nz = e1x*e2y - e1y*e2x;
        float S  = nx*nx + ny*ny + nz*nz + 1e-12f;
        float wt = st / (2.f * sqrtf(S));
        float dx = e1x-e2x, dy = e1y-e2y, dz = e1z-e2z;
        float g0x = wt*(dy*nz - dz*ny), g0y = wt*(dz*nx - dx*nz), g0z = wt*(dx*ny - dy*nx);
        float g1x = wt*(e2y*nz - e2z*ny), g1y = wt*(e2z*nx - e2x*nz), g1z = wt*(e2x*ny - e2y*nx);
        float g2x = wt*(ny*e1z - nz*e1y), g2y = wt*(nz*e1x - nx*e1z), g2z = wt*(nx*e1y - ny*e1x);
        float k = coeff / 6.f;
        atomicAdd(&s_gx[ia], g0x + k*q0x); atomicAdd(&s_gy[ia], g0y + k*q0y); atomicAdd(&s_gz[ia], g0z + k*q0z);
        atomicAdd(&s_gx[ib], g1x + k*q1x); atomicAdd(&s_gy[ib], g1y + k*q1y); atomicAdd(&s_gz[ib], g1z + k*q1z);
        atomicAdd(&s_gx[ic], g2x + k*q2x); atomicAdd(&s_gy[ic], g2y + k*q2y); atomicAdd(&s_gz[ic], g2z + k*q2z);
        atomicAdd(&s_csx, q0x+q1x+q2x);
        atomicAdd(&s_csy, q0y+q1y+q2y);
        atomicAdd(&s_csz, q0z+q1z+q2z);
      }
      __syncthreads();
      if (t < VP) {
        float corr = coeff / 384.f;   // coeff * (1/6) * (1/64) centroid chain
        s_fx[t] = -(s_gx[t] - corr*s_csx);
        s_fy[t] = -(s_gy[t] - corr*s_csy);
        s_fz[t] = -(s_gz[t] - corr*s_csz);
      }
    }
    __syncthreads();
    if (t < VP) {
      int l = s_lab[t];
      bool leader = true;
      for (int s = 0; s < t; ++s) if (s_lab[s] == l) { leader = false; break; }
      if (leader) {
        float sx = 0.f, sy = 0.f, sz = 0.f;
        for (int s = t; s < VP; ++s)
          if (s_lab[s] == l) { sx += s_fx[s]; sy += s_fy[s]; sz += s_fz[s]; }
        atomicAdd(&sums2[3*l+0], sx);
        atomicAdd(&sums2[3*l+1], sy);
        atomicAdd(&sums2[3*l+2], sz);
      }
    }
    gridbar(slots, ++seq, c, t);

    // ===== PHASE 11: Euler update ======================================
    if (t < VP) {
      int i = c*VP + t;
      int l = s_lab[t];
      float cc = fmaxf(ald(&counts1[l]), 1.f);
      ast(&verts[3*i+0], s_vx[t] + 1e-5f*(ald(&sums2[3*l+0])/cc));
      ast(&verts[3*i+1], s_vy[t] + 1e-5f*(ald(&sums2[3*l+1])/cc));
      ast(&verts[3*i+2], s_vz[t] + 1e-5f*(ald(&sums2[3*l+2])/cc));
    }
    if (it != 4) gridbar(slots, ++seq, c, t);
    else { asm volatile("s_waitcnt vmcnt(0)" ::: "memory"); }
  }
}

extern "C" void kernel_launch(void* const* d_in, const int* in_sizes, int n_in,
                              void* d_out, int out_size, void* d_ws, size_t ws_size,
                              hipStream_t stream) {
  const float* inV   = (const float*)d_in[0];
  const float* bb    = (const float*)d_in[1];
  const float* pP    = (const float*)d_in[2];
  const float* pS    = (const float*)d_in[3];
  const int*   faces = (const int*)d_in[4];
  const int*   cfl   = (const int*)d_in[6];

  char* w = (char*)d_ws;
  float* verts   = (float*)w; w += NV*3*sizeof(float);    // 96 KB
  int*   labels2 = (int*)w;   w += NV*sizeof(int);        // 32 KB
  float* sums1   = (float*)w; w += NV*3*sizeof(float);    // 96 KB
  float* counts1 = (float*)w; w += NV*sizeof(float);      // 32 KB
  float* sums2   = (float*)w; w += NV*3*sizeof(float);    // 96 KB
  ull*   masks   = (ull*)w;   w += (size_t)NC*MAXSLOT*VP*sizeof(ull);  // 1.66 MB
  int*   slots   = (int*)w;   w += NBLK*sizeof(int);

  hipMemsetAsync(slots, 0, NBLK*sizeof(int), stream);
  hipMemcpyAsync(verts, inV, NV*3*sizeof(float), hipMemcpyDeviceToDevice, stream);
  soap_fused<<<NBLK, NTHR, 0, stream>>>(bb, pP, pS, faces, cfl,
                                        verts, labels2, sums1, counts1,
                                        sums2, masks, slots);
  hipMemcpyAsync(d_out, verts, NV*3*sizeof(float), hipMemcpyDeviceToDevice, stream);
}

// Round 5
// 682.806 us; speedup vs baseline: 2.4071x; 1.6661x over previous
//
#include <hip/hip_runtime.h>

#define NV 8192
#define NC 128
#define VP 64
#define FP 124
#define NBLK 128
#define NTHR 256
#define MAXSLOT 26   // bbox half-extent <= 0.5, spacing 0.8 -> <=26 neighbors

typedef unsigned long long ull;

// Coherent (MALL-level) accessors: global_load/store with sc1, bypassing the
// non-coherent per-XCD L2. No cache fences needed anywhere.
__device__ __forceinline__ float ald(const float* p) {
  return __hip_atomic_load(p, __ATOMIC_RELAXED, __HIP_MEMORY_SCOPE_AGENT);
}
__device__ __forceinline__ int aldi(const int* p) {
  return __hip_atomic_load(p, __ATOMIC_RELAXED, __HIP_MEMORY_SCOPE_AGENT);
}
__device__ __forceinline__ void ast(float* p, float v) {
  __hip_atomic_store(p, v, __ATOMIC_RELAXED, __HIP_MEMORY_SCOPE_AGENT);
}
__device__ __forceinline__ void asti(int* p, int v) {
  __hip_atomic_store(p, v, __ATOMIC_RELAXED, __HIP_MEMORY_SCOPE_AGENT);
}

// Two-phase counter barrier, low poll traffic: syncv[0]=monotone arrival
// counter, syncv[32]=generation word ((seq<<1)|convergedBit), syncv[64+i]=
// per-UF-round changed-block counters. Only t==0 polls; LDS broadcast after.
// vmcnt(0) drain before arrival => generation visibility implies data
// visibility (all shared data goes through sc1 / MALL).
__device__ __forceinline__ int gridbar(int* syncv, int seq, const int* s_chgp,
                                       int chgIdx, int* s_convp, int t) {
  asm volatile("s_waitcnt vmcnt(0)" ::: "memory");
  __syncthreads();
  if (t == 0) {
    if (chgIdx >= 0 && *s_chgp)
      __hip_atomic_fetch_add(&syncv[64 + chgIdx], 1, __ATOMIC_RELAXED, __HIP_MEMORY_SCOPE_AGENT);
    asm volatile("s_waitcnt vmcnt(0)" ::: "memory");  // chg visible before arrival
    int old = __hip_atomic_fetch_add(&syncv[0], 1, __ATOMIC_RELAXED, __HIP_MEMORY_SCOPE_AGENT);
    int conv;
    if (old == seq * NBLK - 1) {           // last arriver
      int ch = 0;
      if (chgIdx >= 0)
        ch = __hip_atomic_load(&syncv[64 + chgIdx], __ATOMIC_RELAXED, __HIP_MEMORY_SCOPE_AGENT);
      conv = (chgIdx >= 0 && ch == 0) ? 1 : 0;
      __hip_atomic_store(&syncv[32], (seq << 1) | conv, __ATOMIC_RELAXED, __HIP_MEMORY_SCOPE_AGENT);
    } else {
      int g;
      do {
        __builtin_amdgcn_s_sleep(2);
        g = __hip_atomic_load(&syncv[32], __ATOMIC_RELAXED, __HIP_MEMORY_SCOPE_AGENT);
      } while ((g >> 1) < seq);
      conv = g & 1;
    }
    *s_convp = conv;
  }
  __syncthreads();
  return *s_convp;
}

__global__ __launch_bounds__(NTHR, 1)
void soap_fused(const float* __restrict__ bb, const float* __restrict__ pP,
                const float* __restrict__ pS, const int* __restrict__ faces,
                const int* __restrict__ cfl,
                float* __restrict__ verts, int* __restrict__ labels2,
                float* __restrict__ sums1, float* __restrict__ counts1,
                float* __restrict__ sums2, ull* __restrict__ masks,
                int* syncv) {
  const float T2 = (float)(0.3 * 0.3);
  const int c = blockIdx.x;
  const int t = threadIdx.x;
  const int q = t >> 6;   // wave id 0..3
  const int v = t & 63;   // lane id

  __shared__ float s_vx[VP], s_vy[VP], s_vz[VP], s_sq[VP];
  __shared__ float s_gx[VP], s_gy[VP], s_gz[VP];
  __shared__ float s_fx[VP], s_fy[VP], s_fz[VP];
  __shared__ int   s_nm[VP], s_lab[VP], s_old[VP];
  __shared__ int   s_jl[(MAXSLOT + 1) * VP];
  __shared__ int   s_cellmin[MAXSLOT];
  __shared__ int   s_adjcell[MAXSLOT];
  __shared__ int   s_Ksh, s_chg, s_conv;
  __shared__ ull   s_adjw[2];
  __shared__ float s_cx, s_cy, s_cz, s_vol, s_csx, s_csy, s_csz;

  int seq = 0;
  int ufIdx = 0;   // monotone index into changed-counter slots (<=35)

  // ---- adjacency from bboxes (constant across iterations) ----
  if (q < 2) {
    int b = q * 64 + v;
    float anx = bb[c*6+0], any_ = bb[c*6+1], anz = bb[c*6+2];
    float axx = bb[c*6+3], axy = bb[c*6+4], axz = bb[c*6+5];
    float bnx = bb[b*6+0], bny = bb[b*6+1], bnz = bb[b*6+2];
    float bxx = bb[b*6+3], bxy = bb[b*6+4], bxz = bb[b*6+5];
    bool ov = (b != c) && (anx <= bxx) && (any_ <= bxy) && (anz <= bxz) &&
              (bnx <= axx) && (bny <= axy) && (bnz <= axz);
    ull w = __ballot(ov);
    if (v == 0) s_adjw[q] = w;
  }
  __syncthreads();
  if (t == 0) {
    int slot = 0;
    for (int wd = 0; wd < 2; ++wd) {
      ull aw = s_adjw[wd];
      while (aw) {
        int bbit = __ffsll((long long)aw) - 1; aw &= aw - 1;
        if (slot < MAXSLOT) s_adjcell[slot] = wd * 64 + bbit;
        ++slot;
      }
    }
    s_Ksh = slot;   // provably <= 26
  }
  __syncthreads();
  const int K = s_Ksh;

  for (int it = 0; it < 5; ++it) {
    // ===== PHASE 1: stage + zero sums + mask build + UF round 1 ======
    if (t < VP) {
      int i = c*VP + t;
      float x = ald(&verts[3*i]), y = ald(&verts[3*i+1]), z = ald(&verts[3*i+2]);
      s_vx[t] = x; s_vy[t] = y; s_vz[t] = z; s_sq[t] = x*x + y*y + z*z;
      s_nm[t] = i;            // identity label
      ast(&counts1[i], 0.f);
    }
    for (int idx = t; idx < VP*3; idx += NTHR) {
      ast(&sums1[c*VP*3 + idx], 0.f);
      ast(&sums2[c*VP*3 + idx], 0.f);
    }
    __syncthreads();
    {
      int pmv = NV;
      for (int slot = q; slot < K; slot += 4) {
        int bcell = s_adjcell[slot];
        int j = bcell*VP + v;
        float xj = ald(&verts[3*j]), yj = ald(&verts[3*j+1]), zj = ald(&verts[3*j+2]);
        float sqj = xj*xj + yj*yj + zj*zj;
        ull myw = 0;
        for (int vv = 0; vv < VP; ++vv) {
          float d2 = s_sq[vv] + sqj - 2.f*(s_vx[vv]*xj + s_vy[vv]*yj + s_vz[vv]*zj);
          ull w = __ballot(d2 < T2);
          if (v == vv) myw = w;
        }
        masks[((size_t)c*MAXSLOT + slot)*VP + v] = myw;  // block-private, plain
        if (myw) pmv = min(pmv, bcell*VP + __ffsll((long long)myw) - 1);
      }
      atomicMin(&s_nm[v], pmv);
    }
    __syncthreads();
    if (t < VP) asti(&labels2[c*VP + t], s_nm[t]);
    gridbar(syncv, ++seq, &s_chg, -1, &s_conv, t);

    // ===== PHASES 2..8: UF rounds (1 barrier each, early-exit on fixpoint) ==
    bool converged = false;
    for (int r = 1; r < 8 && !converged; ++r) {
      if (t == 0) s_chg = 0;
      // stage jumped labels jl[j]=labels2[labels2[j]] for own + adjacent cells
      for (int slot = q; slot <= K; slot += 4) {
        int bcell = (slot == K) ? c : s_adjcell[slot];
        int x = aldi(&labels2[bcell*VP + v]);
        if (slot == K) s_old[v] = x;      // own pre-jump label of round r-1
        int jl = aldi(&labels2[x]);
        s_jl[slot*VP + v] = jl;
        int mm = jl;
#pragma unroll
        for (int o = 32; o; o >>= 1) mm = min(mm, __shfl_xor(mm, o));
        if (v == 0 && slot < K) s_cellmin[slot] = mm;
      }
      __syncthreads();
      if (t < VP) s_nm[t] = s_jl[K*VP + t];   // own jumped label
      __syncthreads();
      {
        int pm = NV;
        for (int slot = q; slot < K; slot += 4) {
          ull w = masks[((size_t)c*MAXSLOT + slot)*VP + v];
          if (w == ~0ull) pm = min(pm, s_cellmin[slot]);
          else {
            while (w) {
              int bt = __ffsll((long long)w) - 1; w &= w - 1;
              pm = min(pm, s_jl[slot*VP + bt]);
            }
          }
        }
        atomicMin(&s_nm[v], pm);
      }
      __syncthreads();
      if (t < VP) {
        if (s_nm[t] != s_old[t]) s_chg = 1;   // racy-benign LDS flag
        asti(&labels2[c*VP + t], s_nm[t]);
      }
      converged = gridbar(syncv, ++seq, &s_chg, ufIdx++, &s_conv, t) != 0;
    }

    // ===== PHASE 9: final jump + scatter(verts) ========================
    if (t < VP) s_lab[t] = aldi(&labels2[s_nm[t]]);   // labels2[own]==s_nm
    __syncthreads();
    if (t < VP) {
      int l = s_lab[t];
      bool leader = true;
      for (int s = 0; s < t; ++s) if (s_lab[s] == l) { leader = false; break; }
      if (leader) {
        float sx = 0.f, sy = 0.f, sz = 0.f, cn = 0.f;
        for (int s = t; s < VP; ++s)
          if (s_lab[s] == l) { sx += s_vx[s]; sy += s_vy[s]; sz += s_vz[s]; cn += 1.f; }
        atomicAdd(&sums1[3*l+0], sx);
        atomicAdd(&sums1[3*l+1], sy);
        atomicAdd(&sums1[3*l+2], sz);
        atomicAdd(&counts1[l], cn);
      }
    }
    gridbar(syncv, ++seq, &s_chg, -1, &s_conv, t);

    // ===== PHASE 10: gather_replace + cell forces + scatter(forces) ====
    if (t < VP) {
      int l = s_lab[t];
      float cc = fmaxf(ald(&counts1[l]), 1.f);
      s_vx[t] = ald(&sums1[3*l+0]) / cc;
      s_vy[t] = ald(&sums1[3*l+1]) / cc;
      s_vz[t] = ald(&sums1[3*l+2]) / cc;
      s_gx[t] = 0.f; s_gy[t] = 0.f; s_gz[t] = 0.f;
    }
    if (t == 0) { s_vol = 0.f; s_csx = 0.f; s_csy = 0.f; s_csz = 0.f; }
    __syncthreads();
    if (t < VP) {
      float sx = s_vx[t], sy = s_vy[t], sz = s_vz[t];
#pragma unroll
      for (int o = 32; o; o >>= 1) { sx += __shfl_xor(sx, o); sy += __shfl_xor(sy, o); sz += __shfl_xor(sz, o); }
      if (t == 0) { s_cx = sx*(1.f/VP); s_cy = sy*(1.f/VP); s_cz = sz*(1.f/VP); }
    }
    __syncthreads();
    {
      float cx = s_cx, cy = s_cy, cz = s_cz;
      bool act = (t < FP);
      int ia = 0, ib = 0, ic = 0;
      float p0x=0,p0y=0,p0z=0,p1x=0,p1y=0,p1z=0,p2x=0,p2y=0,p2z=0;
      float q0x=0,q0y=0,q0z=0;
      if (act) {
        int f = cfl[c*FP + t];
        ia = faces[3*f+0] - c*VP; ib = faces[3*f+1] - c*VP; ic = faces[3*f+2] - c*VP;
        p0x = s_vx[ia]-cx; p0y = s_vy[ia]-cy; p0z = s_vz[ia]-cz;
        p1x = s_vx[ib]-cx; p1y = s_vy[ib]-cy; p1z = s_vz[ib]-cz;
        p2x = s_vx[ic]-cx; p2y = s_vy[ic]-cy; p2z = s_vz[ic]-cz;
        q0x = p1y*p2z - p1z*p2y;
        q0y = p1z*p2x - p1x*p2z;
        q0z = p1x*p2y - p1y*p2x;
        float term = p0x*q0x + p0y*q0y + p0z*q0z;
        atomicAdd(&s_vol, term);
      }
      __syncthreads();
      float press = pP[0]*190.f + 10.f;
      float st    = pS[0]*0.018f + 0.002f;
      float tv    = expf(press / 2500.f);
      float vol   = s_vol / 6.f;
      float coeff = 2500.f * (vol - tv);
      if (act) {
        float q1x = p2y*p0z - p2z*p0y;
        float q1y = p2z*p0x - p2x*p0z;
        float q1z = p2x*p0y - p2y*p0x;
        float q2x = p0y*p1z - p0z*p1y;
        float q2y = p0z*p1x - p0x*p1z;
        float q2z = p0x*p1y - p0y*p1x;
        float e1x = p1x-p0x, e1y = p1y-p0y, e1z = p1z-p0z;
        float e2x = p2x-p0x, e2y = p2y-p0y, e2z = p2z-p0z;
        float nx = e1y*e2z - e1z*e2y;
        float ny = e1z*e2x - e1x*e2z;
        float nz = e1x*e2y - e1y*e2x;
        float S  = nx*nx + ny*ny + nz*nz + 1e-12f;
        float wt = st / (2.f * sqrtf(S));
        float dx = e1x-e2x, dy = e1y-e2y, dz = e1z-e2z;
        float g0x = wt*(dy*nz - dz*ny), g0y = wt*(dz*nx - dx*nz), g0z = wt*(dx*ny - dy*nx);
        float g1x = wt*(e2y*nz - e2z*ny), g1y = wt*(e2z*nx - e2x*nz), g1z = wt*(e2x*ny - e2y*nx);
        float g2x = wt*(ny*e1z - nz*e1y), g2y = wt*(nz*e1x - nx*e1z), g2z = wt*(nx*e1y - ny*e1x);
        float k = coeff / 6.f;
        atomicAdd(&s_gx[ia], g0x + k*q0x); atomicAdd(&s_gy[ia], g0y + k*q0y); atomicAdd(&s_gz[ia], g0z + k*q0z);
        atomicAdd(&s_gx[ib], g1x + k*q1x); atomicAdd(&s_gy[ib], g1y + k*q1y); atomicAdd(&s_gz[ib], g1z + k*q1z);
        atomicAdd(&s_gx[ic], g2x + k*q2x); atomicAdd(&s_gy[ic], g2y + k*q2y); atomicAdd(&s_gz[ic], g2z + k*q2z);
        atomicAdd(&s_csx, q0x+q1x+q2x);
        atomicAdd(&s_csy, q0y+q1y+q2y);
        atomicAdd(&s_csz, q0z+q1z+q2z);
      }
      __syncthreads();
      if (t < VP) {
        float corr = coeff / 384.f;   // coeff * (1/6) * (1/64) centroid chain
        s_fx[t] = -(s_gx[t] - corr*s_csx);
        s_fy[t] = -(s_gy[t] - corr*s_csy);
        s_fz[t] = -(s_gz[t] - corr*s_csz);
      }
    }
    __syncthreads();
    if (t < VP) {
      int l = s_lab[t];
      bool leader = true;
      for (int s = 0; s < t; ++s) if (s_lab[s] == l) { leader = false; break; }
      if (leader) {
        float sx = 0.f, sy = 0.f, sz = 0.f;
        for (int s = t; s < VP; ++s)
          if (s_lab[s] == l) { sx += s_fx[s]; sy += s_fy[s]; sz += s_fz[s]; }
        atomicAdd(&sums2[3*l+0], sx);
        atomicAdd(&sums2[3*l+1], sy);
        atomicAdd(&sums2[3*l+2], sz);
      }
    }
    gridbar(syncv, ++seq, &s_chg, -1, &s_conv, t);

    // ===== PHASE 11: Euler update ======================================
    if (t < VP) {
      int i = c*VP + t;
      int l = s_lab[t];
      float cc = fmaxf(ald(&counts1[l]), 1.f);
      ast(&verts[3*i+0], s_vx[t] + 1e-5f*(ald(&sums2[3*l+0])/cc));
      ast(&verts[3*i+1], s_vy[t] + 1e-5f*(ald(&sums2[3*l+1])/cc));
      ast(&verts[3*i+2], s_vz[t] + 1e-5f*(ald(&sums2[3*l+2])/cc));
    }
    if (it != 4) gridbar(syncv, ++seq, &s_chg, -1, &s_conv, t);
    else { asm volatile("s_waitcnt vmcnt(0)" ::: "memory"); }
  }
}

extern "C" void kernel_launch(void* const* d_in, const int* in_sizes, int n_in,
                              void* d_out, int out_size, void* d_ws, size_t ws_size,
                              hipStream_t stream) {
  const float* inV   = (const float*)d_in[0];
  const float* bb    = (const float*)d_in[1];
  const float* pP    = (const float*)d_in[2];
  const float* pS    = (const float*)d_in[3];
  const int*   faces = (const int*)d_in[4];
  const int*   cfl   = (const int*)d_in[6];

  char* w = (char*)d_ws;
  float* verts   = (float*)w; w += NV*3*sizeof(float);    // 96 KB
  int*   labels2 = (int*)w;   w += NV*sizeof(int);        // 32 KB
  float* sums1   = (float*)w; w += NV*3*sizeof(float);    // 96 KB
  float* counts1 = (float*)w; w += NV*sizeof(float);      // 32 KB
  float* sums2   = (float*)w; w += NV*3*sizeof(float);    // 96 KB
  ull*   masks   = (ull*)w;   w += (size_t)NC*MAXSLOT*VP*sizeof(ull);  // 1.66 MB
  int*   syncv   = (int*)w;   w += 128*sizeof(int);       // cnt / gen / chg[64]

  hipMemsetAsync(syncv, 0, 128*sizeof(int), stream);
  hipMemcpyAsync(verts, inV, NV*3*sizeof(float), hipMemcpyDeviceToDevice, stream);
  soap_fused<<<NBLK, NTHR, 0, stream>>>(bb, pP, pS, faces, cfl,
                                        verts, labels2, sums1, counts1,
                                        sums2, masks, syncv);
  hipMemcpyAsync(d_out, verts, NV*3*sizeof(float), hipMemcpyDeviceToDevice, stream);
}